// Round 9
// baseline (33.742 us; speedup 1.0000x reference)
//
#include <hip/hip_runtime.h>

// out[b,o] = sum_{i,n} (Ps*tanh(k*(x + Ec*bm)) + bias) * coef
// bm = 1 + c*sg; c = -0.4*sigmoid(-10*(x-prev)); sg = 1/(1 + u*eE),
//   u = exp2(GATE_C*x) [per (b,i), staged], eE = exp2(GATE_C*Ec) [per param, VGPR]
// tanh(a) = 1 - 2*r, r = 1/(1+exp2(kT*inner)); out = base[o] - 2*sum pc*r
//
// R9: LDS-count + conflict + trans attack.
//  - Bank audit: all R2..R8 maps had 4-way conflicts (bank-quad of
//    p[i*8+n] = 4n independent of i; 4 ih values/wave collide). Wave map
//    here: 8 i0 x 8 n per wave, i0 consecutive -> 8 distinct quads. FREE.
//  - Params in 16 VGPRs (4 slots x {Ec,eE,kT,pc}), gathered once/block:
//    per-term LDS = ONE b128 {x,c,u} read (was b128+b64).
//  - u*eE factorization kills gate exp2; fast_rcp (seed+2 Newton, full-
//    rate ops) kills both rcps: 4 trans/term -> 1. Range-safe: u*eE in
//    [4e-18, 4e31], d2 in [1, 1.1e15], reciprocals normal f32.
//  - 16 named-static acc regs (b-loop fully unrolled; rule #20 safe).

#define GATE_C 14.426950408889634f   // 10*log2(e)
#define TANH_C 2.8853900817779268f   // 2*log2(e)

constexpr int B = 512, I = 128, O = 64, NB = 8, BT = 16, TILES = 2, NS = 4;

__device__ __forceinline__ float fast_rcp(float d) {  // d > 0, ~1e-5 rel
  float y = __int_as_float(0x7EF127EA - __float_as_int(d));
  y = y * fmaf(-d, y, 2.f);
  y = y * fmaf(-d, y, 2.f);
  return y;
}

__global__ __launch_bounds__(256, 4) void fe_main(
    const float* __restrict__ x, const float* __restrict__ k,
    const float* __restrict__ Ec, const float* __restrict__ Ps,
    const float* __restrict__ bias, const float* __restrict__ coef,
    float* __restrict__ out)
{
  __shared__ float4 xcu[BT][I];     // {x, c, u, 0} — 32 KB, conflict-free reads
  __shared__ float racc[4][BT];     // per-wave partials per b
  __shared__ float red[4];          // base[o] partials

  const int tid = threadIdx.x;
  const int o  = blockIdx.y;
  const int i0 = tid >> 3, n = tid & 7;   // wave: 8 consecutive i0 x 8 n

  // ---- params -> VGPRs (once per block); base[o] partial ----
  float ecs[NS], ees[NS], kts[NS], pcs[NS];
  float pbase = 0.f;
  #pragma unroll
  for (int s = 0; s < NS; ++s) {
    const int g = ((i0 + 32 * s) * O + o) * NB + n;
    const float E = Ec[g], K = k[g], P = Ps[g], C = coef[g], Bs = bias[g];
    ecs[s] = E;
    ees[s] = __builtin_amdgcn_exp2f(GATE_C * E);
    kts[s] = K * TANH_C;
    pcs[s] = P * C;
    pbase += fmaf(Bs, C, pcs[s]);
  }
  #pragma unroll
  for (int m = 1; m < 64; m <<= 1) pbase += __shfl_xor(pbase, m);
  if ((tid & 63) == 0) red[tid >> 6] = pbase;

  const int w = tid >> 6, l = tid & 63;

  for (int t = 0; t < TILES; ++t) {
    const int b0 = blockIdx.x * (BT * TILES) + t * BT;
    __syncthreads();   // racc/xcu safe to overwrite; red visible at t=0

    // ---- stage {x, c, u}: coalesced global, one-time LDS writes ----
    for (int e = tid; e < BT * I; e += 256) {
      const int bb = e >> 7, i = e & 127;
      const int bg = b0 + bb;
      const float xv = x[bg * I + i];
      const float pv = (bg == 0) ? 0.f : x[(bg - 1) * I + i];
      const float c = -0.4f * __builtin_amdgcn_rcpf(
          1.f + __builtin_amdgcn_exp2f(GATE_C * (xv - pv)));
      const float u = __builtin_amdgcn_exp2f(GATE_C * xv);
      xcu[bb][i] = make_float4(xv, c, u, 0.f);
    }
    __syncthreads();

    // ---- main: 4 slots x 16 b-rows, fully static unroll ----
    float acc[BT];
    #pragma unroll
    for (int b = 0; b < BT; ++b) acc[b] = 0.f;

    #pragma unroll
    for (int s = 0; s < NS; ++s) {
      const float ec = ecs[s], ee = ees[s], kt = kts[s], pc = pcs[s];
      #pragma unroll
      for (int b = 0; b < BT; ++b) {
        const float4 v = xcu[b][i0 + 32 * s];       // conflict-free b128
        const float d1 = fmaf(v.z, ee, 1.f);        // 1 + u*eE
        const float sg = fast_rcp(d1);              // sigmoid(-10(x+Ec))
        const float bm = fmaf(v.y, sg, 1.f);        // 1 + c*sg
        const float inner = fmaf(ec, bm, v.x);      // x + Ec*bm
        const float d2 = 1.f + __builtin_amdgcn_exp2f(kt * inner);
        acc[b] = fmaf(pc, fast_rcp(d2), acc[b]);    // += pc*r
      }
    }

    // ---- reduce: full-wave butterfly per b; lane0 writes (static idx) ----
    #pragma unroll
    for (int b = 0; b < BT; ++b) {
      float a = acc[b];
      a += __shfl_xor(a, 1);  a += __shfl_xor(a, 2);  a += __shfl_xor(a, 4);
      a += __shfl_xor(a, 8);  a += __shfl_xor(a, 16); a += __shfl_xor(a, 32);
      acc[b] = a;
    }
    if (l == 0) {
      #pragma unroll
      for (int b = 0; b < BT; ++b) racc[w][b] = acc[b];
    }
    __syncthreads();

    if (tid < BT) {
      const float base = red[0] + red[1] + red[2] + red[3];
      const float r = racc[0][tid] + racc[1][tid] + racc[2][tid] + racc[3][tid];
      out[(b0 + tid) * O + o] = fmaf(-2.f, r, base);
    }
  }
}

extern "C" void kernel_launch(void* const* d_in, const int* in_sizes, int n_in,
                              void* d_out, int out_size, void* d_ws, size_t ws_size,
                              hipStream_t stream) {
  const float* x    = (const float*)d_in[0];
  const float* k    = (const float*)d_in[1];
  const float* Ec   = (const float*)d_in[2];
  const float* Ps   = (const float*)d_in[3];
  const float* bias = (const float*)d_in[4];
  const float* coef = (const float*)d_in[5];
  float* out = (float*)d_out;

  dim3 grid(B / (BT * TILES), O);   // (16, 64) = 1024 blocks, 4/CU, 1 round
  fe_main<<<grid, 256, 0, stream>>>(x, k, Ec, Ps, bias, coef, out);
}